// Round 3
// baseline (431.236 us; speedup 1.0000x reference)
//
#include <hip/hip_runtime.h>
#include <hip/hip_bf16.h>
#include <cstdint>

#define B_ 8
#define N_ 32768
#define NG_ 32768
#define K1 131
#define K1P 160      // padded K for layer 1 (5 k-steps of 32)
#define N1 1024
#define C2 128
#define MT 64        // points per block (keeps static LDS < 64 KiB)
#define XT_PITCH 168 // bf16 elems
#define A1_PITCH 136 // bf16 elems
#define THREADS 512

typedef __attribute__((ext_vector_type(8))) __bf16 bf16x8;
typedef __attribute__((ext_vector_type(8))) unsigned short ushort8;
typedef __attribute__((ext_vector_type(4))) float f32x4;

// ws layout
#define PW1_ELEMS (64*5*64*8)            // 163840 bf16
#define OFF_PW1 0
#define OFF_PW2 (PW1_ELEMS*2)            // 327680
#define PW2_ELEMS (8*32*64*8)            // 131072 bf16
#define OFF_B2P (OFF_PW2 + PW2_ELEMS*2)  // 589824
#define OFF_S2  (OFF_B2P + 512)
#define OFF_T2  (OFF_S2 + 512)
#define OFF_GRID (1u<<20)
#define GRID_BYTES ((size_t)B_*NG_*C2*4) // 134,217,728

__device__ __forceinline__ unsigned short f2bf(float f) {
  unsigned u = __float_as_uint(f);
  unsigned r = (u + 0x7FFFu + ((u >> 16) & 1u)) >> 16;  // RNE
  return (unsigned short)r;
}
__device__ __forceinline__ bf16x8 as_bf(ushort8 u) {
  return __builtin_bit_cast(bf16x8, u);
}

// ---- prep: pack W1 (131x1024) into layer-1 B-fragment order, zero-padded K ----
__global__ void prep_pw1(const float* __restrict__ W1, unsigned short* __restrict__ pw1) {
  int gid = blockIdx.x*256 + threadIdx.x;
  if (gid >= PW1_ELEMS) return;
  int e = gid & 7;
  int l = (gid >> 3) & 63;
  int rest = gid >> 9;          // jt*5 + ks
  int ks = rest % 5, jt = rest / 5;
  int j = jt*16 + (l & 15);
  int k = ks*32 + 8*(l >> 4) + e;
  float v = (k < K1) ? W1[k*N1 + j] : 0.f;
  pw1[gid] = f2bf(v);
}

// ---- prep: pack s1-folded W2 (1024x128) into layer-2 B-fragment order ----
__global__ void prep_pw2(const float* __restrict__ W2, const float* __restrict__ g1,
                         const float* __restrict__ v1, unsigned short* __restrict__ pw2) {
  int gid = blockIdx.x*256 + threadIdx.x;
  if (gid >= PW2_ELEMS) return;
  int e = gid & 7;
  int l = (gid >> 3) & 63;
  int rest = gid >> 9;          // ct*32 + js
  int js = rest & 31, ct = rest >> 5;
  int c = ct*16 + (l & 15);
  int jj = js*32 + 8*(l >> 4) + e;
  float s1 = g1[jj] * rsqrtf(v1[jj] + 1e-5f);
  pw2[gid] = f2bf(s1 * W2[jj*C2 + c]);
}

// ---- prep: folded bias vectors ----
__global__ void prep_vec(const float* b2, const float* g2, const float* be2, const float* m2,
                         const float* v2, const float* g1, const float* be1, const float* m1,
                         const float* v1, const float* W2,
                         float* b2p, float* s2o, float* t2o) {
  int c = threadIdx.x;
  if (c >= C2) return;
  float s2 = g2[c] * rsqrtf(v2[c] + 1e-5f);
  s2o[c] = s2;
  t2o[c] = be2[c] - m2[c]*s2;
  float acc = b2[c];
  for (int j = 0; j < N1; ++j) {
    float s1 = g1[j] * rsqrtf(v1[j] + 1e-5f);
    float t1 = be1[j] - m1[j]*s1;
    acc += t1 * W2[j*C2 + c];
  }
  b2p[c] = acc;
}

// ---- fused MLP + scatter-max ----
// LAYOUT 0: target is (B, NG, 128) u32 grid in ws
// LAYOUT 1: target is (B, 128, NG) u32 overlaid on d_out
template<int LAYOUT>
__global__ void __launch_bounds__(THREADS)
fused_mlp_scatter(const float* __restrict__ xyz, const float* __restrict__ pf,
                  const float* __restrict__ b1,
                  const unsigned short* __restrict__ pw1,
                  const unsigned short* __restrict__ pw2,
                  const float* __restrict__ b2p, const float* __restrict__ s2v,
                  const float* __restrict__ t2v,
                  unsigned* __restrict__ grid) {
  __shared__ unsigned short Xt[MT*XT_PITCH];
  __shared__ unsigned short A1[MT*A1_PITCH];
  __shared__ int voxl[MT];

  const int tid = threadIdx.x;
  const int b  = blockIdx.y;
  const int n0 = blockIdx.x * MT;

  // stage X^T -> LDS [m][k] bf16, zero-pad k in [131,160)
  {
    const int m = tid & (MT-1), cg = tid >> 6;   // 8 column groups
    for (int c = cg; c < K1P; c += 8) {
      float v = 0.f;
      if (c < 3)       v = xyz[((size_t)b*3 + c)*N_ + n0 + m];
      else if (c < K1) v = pf[((size_t)b*C2 + (c-3))*N_ + n0 + m];
      Xt[m*XT_PITCH + c] = f2bf(v);
    }
  }
  if (tid < MT) {
    float px = xyz[((size_t)b*3 + 0)*N_ + n0 + tid];
    float py = xyz[((size_t)b*3 + 1)*N_ + n0 + tid];
    float pz = xyz[((size_t)b*3 + 2)*N_ + n0 + tid];
    int ix = min(max((int)floorf((px + 0.5f)*32.f), 0), 31);
    int iy = min(max((int)floorf((py + 0.5f)*32.f), 0), 31);
    int iz = min(max((int)floorf((pz + 0.5f)*32.f), 0), 31);
    voxl[tid] = ix*1024 + iy*32 + iz;
  }
  __syncthreads();

  const int wave = tid >> 6, lane = tid & 63;
  const int lr = lane & 15, lq = lane >> 4;

  f32x4 z2[4];
  #pragma unroll
  for (int mt = 0; mt < 4; ++mt) z2[mt] = (f32x4){0.f,0.f,0.f,0.f};

  for (int ch = 0; ch < 8; ++ch) {
    const int jt = ch*8 + wave;      // global 16-wide j-tile
    f32x4 c1[4];
    #pragma unroll
    for (int mt = 0; mt < 4; ++mt) c1[mt] = (f32x4){0.f,0.f,0.f,0.f};
    bf16x8 bw[5];
    #pragma unroll
    for (int ks = 0; ks < 5; ++ks)
      bw[ks] = as_bf(*(const ushort8*)(pw1 + ((size_t)(jt*5 + ks)*64 + lane)*8));
    #pragma unroll
    for (int mt = 0; mt < 4; ++mt) {
      const unsigned short* xrow = Xt + (mt*16 + lr)*XT_PITCH + 8*lq;
      #pragma unroll
      for (int ks = 0; ks < 5; ++ks) {
        bf16x8 a = as_bf(*(const ushort8*)(xrow + ks*32));
        c1[mt] = __builtin_amdgcn_mfma_f32_16x16x32_bf16(a, bw[ks], c1[mt], 0, 0, 0);
      }
    }
    const float bb1 = b1[jt*16 + lr];
    __syncthreads();                 // prev chunk's layer-2 reads of A1 done
    const int jl = wave*16 + lr;
    #pragma unroll
    for (int mt = 0; mt < 4; ++mt) {
      #pragma unroll
      for (int i = 0; i < 4; ++i) {
        float v = fmaxf(c1[mt][i] + bb1, 0.f);
        A1[(mt*16 + 4*lq + i)*A1_PITCH + jl] = f2bf(v);
      }
    }
    __syncthreads();                 // A1 visible
    #pragma unroll
    for (int ks2 = 0; ks2 < 4; ++ks2) {
      const int js = ch*4 + ks2;
      bf16x8 bw2 = as_bf(*(const ushort8*)(pw2 + ((size_t)(wave*32 + js)*64 + lane)*8));
      #pragma unroll
      for (int mt = 0; mt < 4; ++mt) {
        bf16x8 a2 = as_bf(*(const ushort8*)(A1 + (mt*16 + lr)*A1_PITCH + ks2*32 + 8*lq));
        z2[mt] = __builtin_amdgcn_mfma_f32_16x16x32_bf16(a2, bw2, z2[mt], 0, 0, 0);
      }
    }
  }

  // epilogue: bias + relu + BN2 affine, then scatter-max (order-preserving uint encode)
  const int c = wave*16 + lr;
  const float bc = b2p[c], sc = s2v[c], tc = t2v[c];
  unsigned* gb = grid + (size_t)b*NG_*C2;
  #pragma unroll
  for (int mt = 0; mt < 4; ++mt) {
    #pragma unroll
    for (int i = 0; i < 4; ++i) {
      const int m = mt*16 + 4*lq + i;
      float v = fmaxf(z2[mt][i] + bc, 0.f)*sc + tc;
      unsigned u = __float_as_uint(v);
      unsigned enc = (u & 0x80000000u) ? ~u : (u | 0x80000000u);
      if (LAYOUT == 0)
        atomicMax(gb + (size_t)voxl[m]*C2 + c, enc);
      else
        atomicMax(gb + (size_t)c*NG_ + voxl[m], enc);
    }
  }
}

// ---- decode + transpose: (B,NG,128) encoded -> (B,128,NG) f32, empty->0 ----
__global__ void decode_transpose(const unsigned* __restrict__ grid, float* __restrict__ out) {
  __shared__ float t[64][129];
  const int b = blockIdx.y, v0 = blockIdx.x*64;
  const int tid = threadIdx.x;
  const unsigned* g = grid + ((size_t)b*NG_ + v0)*C2;
  for (int idx = tid; idx < 64*C2; idx += 256) {
    unsigned u = g[idx];
    float f = 0.f;
    if (u) {
      unsigned bits = (u & 0x80000000u) ? (u & 0x7FFFFFFFu) : ~u;
      f = __uint_as_float(bits);
    }
    t[idx >> 7][idx & 127] = f;
  }
  __syncthreads();
  float* o = out + (size_t)b*C2*NG_ + v0;
  for (int idx = tid; idx < 64*C2; idx += 256) {
    int c = idx >> 6, vv = idx & 63;
    o[(size_t)c*NG_ + vv] = t[vv][c];
  }
}

// ---- in-place decode for LAYOUT 1 ----
__global__ void decode_inplace(unsigned* __restrict__ buf, size_t n) {
  size_t i = (size_t)blockIdx.x*256 + threadIdx.x;
  if (i >= n) return;
  unsigned u = buf[i];
  float f = 0.f;
  if (u) {
    unsigned bits = (u & 0x80000000u) ? (u & 0x7FFFFFFFu) : ~u;
    f = __uint_as_float(bits);
  }
  ((float*)buf)[i] = f;
}

extern "C" void kernel_launch(void* const* d_in, const int* in_sizes, int n_in,
                              void* d_out, int out_size, void* d_ws, size_t ws_size,
                              hipStream_t stream) {
  const float* xyz = (const float*)d_in[0];
  const float* pf  = (const float*)d_in[1];
  const float* W1  = (const float*)d_in[2];
  const float* b1  = (const float*)d_in[3];
  const float* g1  = (const float*)d_in[4];
  const float* be1 = (const float*)d_in[5];
  const float* m1  = (const float*)d_in[6];
  const float* v1  = (const float*)d_in[7];
  const float* W2  = (const float*)d_in[8];
  const float* b2  = (const float*)d_in[9];
  const float* g2  = (const float*)d_in[10];
  const float* be2 = (const float*)d_in[11];
  const float* m2  = (const float*)d_in[12];
  const float* v2  = (const float*)d_in[13];

  char* ws = (char*)d_ws;
  unsigned short* pw1 = (unsigned short*)(ws + OFF_PW1);
  unsigned short* pw2 = (unsigned short*)(ws + OFF_PW2);
  float* b2p = (float*)(ws + OFF_B2P);
  float* s2v = (float*)(ws + OFF_S2);
  float* t2v = (float*)(ws + OFF_T2);

  prep_pw1<<<(PW1_ELEMS + 255)/256, 256, 0, stream>>>(W1, pw1);
  prep_pw2<<<(PW2_ELEMS + 255)/256, 256, 0, stream>>>(W2, g1, v1, pw2);
  prep_vec<<<1, 128, 0, stream>>>(b2, g2, be2, m2, v2, g1, be1, m1, v1, W2, b2p, s2v, t2v);

  const bool use_ws_grid = (ws_size >= (size_t)OFF_GRID + GRID_BYTES);

  if (use_ws_grid) {
    unsigned* grid = (unsigned*)(ws + OFF_GRID);
    hipMemsetAsync(grid, 0, GRID_BYTES, stream);
    fused_mlp_scatter<0><<<dim3(N_/MT, B_), THREADS, 0, stream>>>(
        xyz, pf, b1, pw1, pw2, b2p, s2v, t2v, grid);
    decode_transpose<<<dim3(NG_/64, B_), 256, 0, stream>>>(grid, (float*)d_out);
  } else {
    unsigned* grid = (unsigned*)d_out;
    hipMemsetAsync(grid, 0, GRID_BYTES, stream);
    fused_mlp_scatter<1><<<dim3(N_/MT, B_), THREADS, 0, stream>>>(
        xyz, pf, b1, pw1, pw2, b2p, s2v, t2v, grid);
    size_t n = (size_t)B_*C2*NG_;
    decode_inplace<<<(unsigned)((n + 255)/256), 256, 0, stream>>>(grid, n);
  }
}